// Round 2
// baseline (140.268 us; speedup 1.0000x reference)
//
#include <hip/hip_runtime.h>
#include <math.h>

// HOG-3D: central-difference gradients -> (theta,phi) soft-binned histogram scatter.
// Output (1,8,8,78,78,78) fp32 = 121.5 MB.
//
// R4 (= R3 with compile fix): __builtin_nontemporal_store needs a clang
// ext_vector type, not HIP's float4 class. Same plan:
// The timed graph is [harness poison fill ~74us] + [this kernel]. The fill is
// untouchable; our kernel was ~55us = 2.2 TB/s effective write BW. Cause: one
// voxel/thread -> each wave stores 256B per plane across 64 planes = ~7400
// concurrent 256B write streams -> DRAM row thrash.
// Fix: 4 consecutive voxels/thread, one 16B non-temporal store per plane
// -> 1KB contiguous per wave per plane, 4x fewer streams + store instrs.
//
// Numerics (unchanged from R2, bit-exact vs the f32 numpy chain):
//  - every arithmetic op done in f32, same order as numpy (IEEE ops are
//    correctly rounded -> bitwise match given same operands/order)
//  - atan2f/acosf computed as f64 libm rounded to f32 = correctly-rounded f32
//  - fp contract OFF so mag2 isn't FMA-contracted (would differ from numpy)

#define DVOL 64
#define S 78              // 64 + 2*8 - 2
#define S3 (S * S * S)    // 474552
#define S3_4 (S3 / 4)     // 118638  (S3 % 4 == 0)

typedef float f32x4 __attribute__((ext_vector_type(4)));

__device__ __forceinline__ float ldx(const float* __restrict__ x, int z, int y, int xx) {
    if ((unsigned)z < (unsigned)DVOL && (unsigned)y < (unsigned)DVOL && (unsigned)xx < (unsigned)DVOL)
        return x[(z * DVOL + y) * DVOL + xx];
    return 0.0f;
}

__global__ void __launch_bounds__(256) hog_scatter4(const float* __restrict__ x,
                                                    f32x4* __restrict__ out) {
#pragma clang fp contract(off)
    int t4 = blockIdx.x * 256 + threadIdx.x;
    if (t4 >= S3_4) return;

    // Per-voxel deposit state for the 4 consecutive voxels this thread owns.
    float wv0[4], wv1[4], wv2[4];
    int   b0[4],  b1[4],  b2[4];

    #pragma unroll
    for (int e = 0; e < 4; ++e) {
        int idx = t4 * 4 + e;
        int ox = idx % S;
        int r  = idx / S;
        int oy = r % S;
        int oz = r / S;
        int ix = ox - 7, iy = oy - 7, iz = oz - 7;

        // f32 central differences (IEEE subtract == numpy bitwise)
        float gz = ldx(x, iz + 1, iy, ix) - ldx(x, iz - 1, iy, ix);
        float gy = ldx(x, iz, iy + 1, ix) - ldx(x, iz, iy - 1, ix);
        float gx = ldx(x, iz, iy, ix + 1) - ldx(x, iz, iy, ix - 1);

        // np.sum(out*out, axis=0) order: ((c0^2 + c1^2) + c2^2), all f32, no FMA
        float mag2 = (gz * gz + gy * gy) + gx * gx;
        float mag  = sqrtf(mag2);                      // IEEE sqrt

        wv0[e] = 0.0f; wv1[e] = 0.0f; wv2[e] = 0.0f;
        b0[e] = -1; b1[e] = -1; b2[e] = -1;

        if (mag != 0.0f) {
            // correctly-rounded f32 atan2/acos via f64 libm
            float theta = (float)atan2((double)gy, (double)gx);
            const float EPS32 = 2.220446049250313e-16f;   // 2^-52, exact in f32
            float denom = mag + EPS32;                    // f32 add (== numpy)
            float ratio = gz / denom;                     // IEEE f32 divide
            float phi = (float)acos((double)ratio);

            const float PI32 = 3.14159274101257324f;      // (float)math.pi
            float t_raw = theta / PI32 * 8.0f;            // f32 div, then *8 (exact)
            float p_raw = phi   / PI32 * 8.0f;

            float t_frac = t_raw - truncf(t_raw);         // torch.frac (signed), exact
            float p_frac = p_raw - truncf(p_raw);

            // numpy floored-mod, pow2 divisor -> two's-complement AND
            int i0 = ((int)floorf(t_raw)) & 7;
            int i1 = ((int)ceilf (t_raw)) & 7;
            int i2 = ((int)floorf(p_raw)) & 7;
            int i3 = ((int)ceilf (p_raw)) & 7;

            float f0 = fabsf(t_frac), f1 = fabsf(1.0f - t_frac);
            float f2 = fabsf(p_frac), f3 = fabsf(1.0f - p_frac);
            float w0 = (f0 * f2) * mag;   // -> (i0, i2)
            float w1 = (f0 * f3) * mag;   // -> (i0, i3)
            float w2 = (f1 * f2) * mag;   // -> (i1, i2)

            int c0 = i0 * 8 + i2, c1 = i0 * 8 + i3, c2 = i1 * 8 + i2;
            // merge colliding deposits in the reference add order ((w0+w1)+w2)
            if (c1 == c0) { w0 = w0 + w1; c1 = -1; }
            if (c2 == c0) { w0 = w0 + w2; c2 = -1; }
            // (c2==c1 with c1!=c0 is impossible: would require i1==i0 && i3==i2)

            wv0[e] = w0; wv1[e] = w1; wv2[e] = w2;
            b0[e]  = c0; b1[e]  = c1; b2[e]  = c2;
        }
    }

    // Write the full 64-plane column for 4 consecutive voxels: one 16B
    // non-temporal store per plane -> 1KB contiguous per wave per plane.
    // All array indices compile-time constant (full unroll) -> registers.
    #pragma unroll
    for (int p = 0; p < 64; ++p) {
        f32x4 o;
        #pragma unroll
        for (int e = 0; e < 4; ++e) {
            float v = 0.0f;
            if (p == b0[e]) v = wv0[e];
            if (p == b1[e]) v = wv1[e];
            if (p == b2[e]) v = wv2[e];
            o[e] = v;
        }
        __builtin_nontemporal_store(o, &out[(size_t)p * S3_4 + t4]);
    }
}

extern "C" void kernel_launch(void* const* d_in, const int* in_sizes, int n_in,
                              void* d_out, int out_size, void* d_ws, size_t ws_size,
                              hipStream_t stream) {
    const float* x = (const float*)d_in[0];   // (64,64,64) fp32
    // d_in[1] (sobel weight) is a fixed constant per the reference -- folded in.
    f32x4* out = (f32x4*)d_out;

    const int threads = 256;
    const int blocks = (S3_4 + threads - 1) / threads;   // 464
    hog_scatter4<<<blocks, threads, 0, stream>>>(x, out);
}

// Round 3
// 130.590 us; speedup vs baseline: 1.0741x; 1.0741x over previous
//
#include <hip/hip_runtime.h>
#include <math.h>

// HOG-3D: central-difference gradients -> (theta,phi) soft-binned histogram scatter.
// Output (1,8,8,78,78,78) fp32 = 121.5 MB.
//
// R5: two-pass restructure. Evidence: harness fill streams 486 MB at 6.2 TB/s
// linearly; our single-pass kernel wrote 121.5 MB at ~2.1 TB/s because every
// thread round-robins 64 planes -> concurrent write window = whole 121.5 MB
// (poor row/TLB/L2-writeback locality). Burst-width (R4: 1KB/wave/plane) was
// neutral -> the lever is the GLOBAL window, which needs grid-level ordering:
//   pass1: per-voxel polar record {t_raw, p_raw, mag} (f64 libm done ONCE)
//          -> 5.7 MB SoA in d_ws.
//   pass2: grid theta-row-major (8 groups x 8 planes); threads re-derive
//          bins/weights from records (cheap exact f32) and write 8 planes.
//          Concurrent blocks sit in 1-2 groups -> dense fill-like writes.
// Fallback to single-pass if ws_size too small.
//
// Numerics: identical f32 chain as before. Records hold t_raw/p_raw/mag; all
// downstream ops (trunc/floor/ceil/fabs/mul) are deterministic exact f32 in
// the same order as numpy -> bitwise-identical output.

#define DVOL 64
#define S 78              // 64 + 2*8 - 2
#define S3 (S * S * S)    // 474552
#define S3_4 (S3 / 4)     // 118638
#define CHUNKS ((S3_4 + 255) / 256)   // 464 blocks per plane-group

typedef float f32x4 __attribute__((ext_vector_type(4)));

__device__ __forceinline__ float ldx(const float* __restrict__ x, int z, int y, int xx) {
    if ((unsigned)z < (unsigned)DVOL && (unsigned)y < (unsigned)DVOL && (unsigned)xx < (unsigned)DVOL)
        return x[(z * DVOL + y) * DVOL + xx];
    return 0.0f;
}

// ---- pass 1: gradients + f64 libm -> polar record SoA {t_raw, p_raw, mag} ----
__global__ void __launch_bounds__(256) hog_pass1(const float* __restrict__ x,
                                                 float* __restrict__ tr,
                                                 float* __restrict__ pr,
                                                 float* __restrict__ mg) {
#pragma clang fp contract(off)
    int idx = blockIdx.x * 256 + threadIdx.x;
    if (idx >= S3) return;
    int ox = idx % S;
    int r  = idx / S;
    int oy = r % S;
    int oz = r / S;
    int ix = ox - 7, iy = oy - 7, iz = oz - 7;

    // f32 central differences (IEEE subtract == numpy bitwise)
    float gz = ldx(x, iz + 1, iy, ix) - ldx(x, iz - 1, iy, ix);
    float gy = ldx(x, iz, iy + 1, ix) - ldx(x, iz, iy - 1, ix);
    float gx = ldx(x, iz, iy, ix + 1) - ldx(x, iz, iy, ix - 1);

    // ((c0^2 + c1^2) + c2^2), all f32, no FMA
    float mag2 = (gz * gz + gy * gy) + gx * gx;
    float mag  = sqrtf(mag2);                      // IEEE sqrt

    float t_raw = 0.0f, p_raw = 0.0f;
    if (mag != 0.0f) {
        // correctly-rounded f32 atan2/acos via f64 libm
        float theta = (float)atan2((double)gy, (double)gx);
        const float EPS32 = 2.220446049250313e-16f;   // 2^-52, exact in f32
        float denom = mag + EPS32;                    // f32 add (== numpy)
        float ratio = gz / denom;                     // IEEE f32 divide
        float phi = (float)acos((double)ratio);

        const float PI32 = 3.14159274101257324f;      // (float)math.pi
        t_raw = theta / PI32 * 8.0f;                  // f32 div, then *8 (exact)
        p_raw = phi   / PI32 * 8.0f;
    }
    // mag==0 -> record (0,0,0); pass2 then deposits w=...*0 = 0 everywhere.
    tr[idx] = t_raw;
    pr[idx] = p_raw;
    mg[idx] = mag;
}

// ---- pass 2: theta-row-major dense writes ----
// blockIdx = g*CHUNKS + c ; group g owns planes [g*8, g*8+8).
// Each thread: 4 consecutive voxels x 8 planes of group g.
__global__ void __launch_bounds__(256) hog_pass2(const float* __restrict__ tr,
                                                 const float* __restrict__ pr,
                                                 const float* __restrict__ mg,
                                                 f32x4* __restrict__ out) {
#pragma clang fp contract(off)
    int g = blockIdx.x / CHUNKS;
    int c = blockIdx.x % CHUNKS;
    int t4 = c * 256 + threadIdx.x;
    if (t4 >= S3_4) return;

    const f32x4 trv = reinterpret_cast<const f32x4*>(tr)[t4];
    const f32x4 prv = reinterpret_cast<const f32x4*>(pr)[t4];
    const f32x4 mgv = reinterpret_cast<const f32x4*>(mg)[t4];

    f32x4 acc[8];   // compile-time indexed only (full unroll) -> registers
    #pragma unroll
    for (int p = 0; p < 8; ++p) acc[p] = (f32x4)(0.0f);

    #pragma unroll
    for (int e = 0; e < 4; ++e) {
        float t_raw = trv[e], p_raw = prv[e], mag = mgv[e];

        float t_frac = t_raw - truncf(t_raw);         // torch.frac, exact
        float p_frac = p_raw - truncf(p_raw);

        int i0 = ((int)floorf(t_raw)) & 7;            // floored-mod pow2
        int i1 = ((int)ceilf (t_raw)) & 7;
        int i2 = ((int)floorf(p_raw)) & 7;
        int i3 = ((int)ceilf (p_raw)) & 7;

        float f0 = fabsf(t_frac), f1 = fabsf(1.0f - t_frac);
        float f2 = fabsf(p_frac), f3 = fabsf(1.0f - p_frac);
        float w0 = (f0 * f2) * mag;   // -> (i0, i2)
        float w1 = (f0 * f3) * mag;   // -> (i0, i3)
        float w2 = (f1 * f2) * mag;   // -> (i1, i2)

        int b0 = i0 * 8 + i2, b1 = i0 * 8 + i3, b2 = i1 * 8 + i2;
        // merge colliding deposits in the reference add order ((w0+w1)+w2)
        if (b1 == b0) { w0 = w0 + w1; b1 = -1; }
        if (b2 == b0) { w0 = w0 + w2; b2 = -1; }
        // (b2==b1 with b1!=b0 impossible: needs i1==i0 && i3==i2 -> all equal)

        #pragma unroll
        for (int p = 0; p < 8; ++p) {
            int bin = g * 8 + p;
            float v = (bin == b0) ? w0 : ((bin == b1) ? w1 : ((bin == b2) ? w2 : 0.0f));
            acc[p][e] = v;
        }
    }

    #pragma unroll
    for (int p = 0; p < 8; ++p) {
        out[(size_t)(g * 8 + p) * S3_4 + t4] = acc[p];
    }
}

// ---- fallback: single-pass (R4 structure, plain stores, no nt) ----
__global__ void __launch_bounds__(256) hog_single(const float* __restrict__ x,
                                                  f32x4* __restrict__ out) {
#pragma clang fp contract(off)
    int t4 = blockIdx.x * 256 + threadIdx.x;
    if (t4 >= S3_4) return;

    float wv0[4], wv1[4], wv2[4];
    int   b0[4],  b1[4],  b2[4];

    #pragma unroll
    for (int e = 0; e < 4; ++e) {
        int idx = t4 * 4 + e;
        int ox = idx % S;
        int r  = idx / S;
        int oy = r % S;
        int oz = r / S;
        int ix = ox - 7, iy = oy - 7, iz = oz - 7;

        float gz = ldx(x, iz + 1, iy, ix) - ldx(x, iz - 1, iy, ix);
        float gy = ldx(x, iz, iy + 1, ix) - ldx(x, iz, iy - 1, ix);
        float gx = ldx(x, iz, iy, ix + 1) - ldx(x, iz, iy, ix - 1);

        float mag2 = (gz * gz + gy * gy) + gx * gx;
        float mag  = sqrtf(mag2);

        wv0[e] = 0.0f; wv1[e] = 0.0f; wv2[e] = 0.0f;
        b0[e] = -1; b1[e] = -1; b2[e] = -1;

        if (mag != 0.0f) {
            float theta = (float)atan2((double)gy, (double)gx);
            const float EPS32 = 2.220446049250313e-16f;
            float denom = mag + EPS32;
            float ratio = gz / denom;
            float phi = (float)acos((double)ratio);

            const float PI32 = 3.14159274101257324f;
            float t_raw = theta / PI32 * 8.0f;
            float p_raw = phi   / PI32 * 8.0f;

            float t_frac = t_raw - truncf(t_raw);
            float p_frac = p_raw - truncf(p_raw);

            int i0 = ((int)floorf(t_raw)) & 7;
            int i1 = ((int)ceilf (t_raw)) & 7;
            int i2 = ((int)floorf(p_raw)) & 7;
            int i3 = ((int)ceilf (p_raw)) & 7;

            float f0 = fabsf(t_frac), f1 = fabsf(1.0f - t_frac);
            float f2 = fabsf(p_frac), f3 = fabsf(1.0f - p_frac);
            float w0 = (f0 * f2) * mag;
            float w1 = (f0 * f3) * mag;
            float w2 = (f1 * f2) * mag;

            int c0 = i0 * 8 + i2, c1 = i0 * 8 + i3, c2 = i1 * 8 + i2;
            if (c1 == c0) { w0 = w0 + w1; c1 = -1; }
            if (c2 == c0) { w0 = w0 + w2; c2 = -1; }

            wv0[e] = w0; wv1[e] = w1; wv2[e] = w2;
            b0[e]  = c0; b1[e]  = c1; b2[e]  = c2;
        }
    }

    #pragma unroll
    for (int p = 0; p < 64; ++p) {
        f32x4 o;
        #pragma unroll
        for (int e = 0; e < 4; ++e) {
            float v = 0.0f;
            if (p == b0[e]) v = wv0[e];
            if (p == b1[e]) v = wv1[e];
            if (p == b2[e]) v = wv2[e];
            o[e] = v;
        }
        out[(size_t)p * S3_4 + t4] = o;
    }
}

extern "C" void kernel_launch(void* const* d_in, const int* in_sizes, int n_in,
                              void* d_out, int out_size, void* d_ws, size_t ws_size,
                              hipStream_t stream) {
    const float* x = (const float*)d_in[0];   // (64,64,64) fp32
    f32x4* out = (f32x4*)d_out;

    const size_t need = (size_t)S3 * 3 * sizeof(float);   // 5.69 MB record SoA
    if (d_ws != nullptr && ws_size >= need) {
        float* tr = (float*)d_ws;
        float* pr = tr + S3;
        float* mg = tr + 2 * (size_t)S3;
        hog_pass1<<<(S3 + 255) / 256, 256, 0, stream>>>(x, tr, pr, mg);
        hog_pass2<<<8 * CHUNKS, 256, 0, stream>>>(tr, pr, mg, out);
    } else {
        hog_single<<<CHUNKS, 256, 0, stream>>>(x, out);
    }
}